// Round 9
// baseline (21500.659 us; speedup 1.0000x reference)
//
#include <hip/hip_runtime.h>
#include <hip/hip_fp16.h>

#define USER_NUM 200000
#define ITEM_NUM 100000
#define N_NODES  300000   // USER_NUM + ITEM_NUM
#define N_EDGES  9600000
#define D        64
#define NELEM    ((long long)N_NODES * D)       // 19,200,000
#define NELEM4   (NELEM / 4)                    // 4,800,000

// seg entry: u64 = (local_node << 32) | (q << 19) | src.
// q = 13-bit weight (w = q/8191), src = 19-bit node id.
#define SRC_MASK 0x7FFFFu
#define W_SCALE  (1.0f / 8191.0f)

// ---- fused-build geometry ----
// binA (proven r6 structure): block-local counting sort of EPB edges by
// dst-bin, staged in LDS (no line thrash), streamed out full-line.
// binB/slots/deg DELETED (r8 lesson: ~140 us of pure re-shuffle): spmm
// accumulates directly into per-bin LDS fp32 accumulators while walking
// the bin's seg fragments (binB's latency-tolerant walk, r7's failure was
// per-(node,slice) runs of 1.33 — fragments avg ~4 edges, wave-lockstep).
#define BIN_NODES 192
#define NBINS     1563          // ceil(300000/192); 1563*192 = 300,096
#define EPB       6144          // edges per binA block (48 KB u64 stage)
#define NBLK_A    1563          // ceil(9.6M/6144); last block nE = 3072
#define ACC_STR   65            // acc stride: bank=(l+4c+k)%32 -> 2-way (free)

// ---------------------------------------------------------------- init
// cur = fp16(all_emb). Final layer reconstructs the layer-sum from the
// per-layer fp16 buffers, so out is never RMW'd across layers.
__global__ void init_kernel(const float4* __restrict__ user_emb,
                            const float4* __restrict__ item_emb,
                            ushort4* __restrict__ cur) {
    long long i = (long long)blockIdx.x * blockDim.x + threadIdx.x;
    if (i >= NELEM4) return;
    const long long user4 = (long long)USER_NUM * D / 4;
    float4 v = (i < user4) ? user_emb[i] : item_emb[i - user4];
    __half h0 = __float2half_rn(v.x), h1 = __float2half_rn(v.y);
    __half h2 = __float2half_rn(v.z), h3 = __float2half_rn(v.w);
    cur[i] = make_ushort4(*(unsigned short*)&h0, *(unsigned short*)&h1,
                          *(unsigned short*)&h2, *(unsigned short*)&h3);
}

// ---------------------------------------------------------------- pass A
// Block-local counting sort of EPB edges by dst-bin (bin = dst/192), staged
// in LDS, streamed out full-line. blk_info[bin][blk] = (start<<16) | count.
__global__ __launch_bounds__(512) void binA_kernel(
        const int*   __restrict__ src,
        const int*   __restrict__ dst,
        const float* __restrict__ w,
        unsigned long long* __restrict__ seg,
        unsigned*           __restrict__ blk_info) {
    __shared__ unsigned long long stage[EPB];   // 49,152 B
    __shared__ int hist[NBINS];                 //  6,252 B
    __shared__ int off[NBINS];                  //  6,252 B -> 61.7 KB, 2 blk/CU
    const int tid = threadIdx.x;
    const long long e0 = (long long)blockIdx.x * EPB;
    long long rem = (long long)N_EDGES - e0;
    const int nE = (int)(rem < EPB ? rem : EPB);   // always a multiple of 4

    for (int i = tid; i < NBINS; i += 512) hist[i] = 0;
    __syncthreads();

    // phase 1: histogram over bins (LDS atomics), int4 loads
    for (int k = tid * 4; k < nE; k += 512 * 4) {
        int4 d4 = *(const int4*)(dst + e0 + k);
        atomicAdd(&hist[(unsigned)d4.x / BIN_NODES], 1);
        atomicAdd(&hist[(unsigned)d4.y / BIN_NODES], 1);
        atomicAdd(&hist[(unsigned)d4.z / BIN_NODES], 1);
        atomicAdd(&hist[(unsigned)d4.w / BIN_NODES], 1);
    }
    __syncthreads();

    // phase 2: exclusive scan over 1563 bins (4/thread chunk + Hillis-Steele)
    const int idx0 = tid * 4;
    int c0 = (idx0 + 0 < NBINS) ? hist[idx0 + 0] : 0;
    int c1 = (idx0 + 1 < NBINS) ? hist[idx0 + 1] : 0;
    int c2 = (idx0 + 2 < NBINS) ? hist[idx0 + 2] : 0;
    int c3 = (idx0 + 3 < NBINS) ? hist[idx0 + 3] : 0;
    __syncthreads();
    hist[tid] = c0 + c1 + c2 + c3;
    __syncthreads();
    for (int s = 1; s < 512; s <<= 1) {
        int v = (tid >= s) ? hist[tid - s] : 0;
        __syncthreads();
        if (tid >= s) hist[tid] += v;
        __syncthreads();
    }
    int b = (tid > 0) ? hist[tid - 1] : 0;
    if (idx0 + 0 < NBINS) { off[idx0 + 0] = b;
        blk_info[(long long)(idx0 + 0) * NBLK_A + blockIdx.x] =
            ((unsigned)b << 16) | (unsigned)c0; b += c0; }
    if (idx0 + 1 < NBINS) { off[idx0 + 1] = b;
        blk_info[(long long)(idx0 + 1) * NBLK_A + blockIdx.x] =
            ((unsigned)b << 16) | (unsigned)c1; b += c1; }
    if (idx0 + 2 < NBINS) { off[idx0 + 2] = b;
        blk_info[(long long)(idx0 + 2) * NBLK_A + blockIdx.x] =
            ((unsigned)b << 16) | (unsigned)c2; b += c2; }
    if (idx0 + 3 < NBINS) { off[idx0 + 3] = b;
        blk_info[(long long)(idx0 + 3) * NBLK_A + blockIdx.x] =
            ((unsigned)b << 16) | (unsigned)c3; }
    __syncthreads();

    // phase 3: scatter into LDS stage (8-B LDS writes: no line thrash)
    for (int k = tid * 4; k < nE; k += 512 * 4) {
        int4   s4 = *(const int4*)(src + e0 + k);
        int4   d4 = *(const int4*)(dst + e0 + k);
        float4 w4 = *(const float4*)(w + e0 + k);
#define DO_EDGE(S, DD, W) { \
        unsigned q = (unsigned)((W) * 8191.0f + 0.5f); \
        unsigned bin = (unsigned)(DD) / BIN_NODES; \
        unsigned loc = (unsigned)(DD) - bin * BIN_NODES; \
        int pos = atomicAdd(&off[bin], 1); \
        stage[pos] = ((unsigned long long)loc << 32) \
                   | ((q << 19) | (unsigned)(S)); }
        DO_EDGE(s4.x, d4.x, w4.x)
        DO_EDGE(s4.y, d4.y, w4.y)
        DO_EDGE(s4.z, d4.z, w4.z)
        DO_EDGE(s4.w, d4.w, w4.w)
#undef DO_EDGE
    }
    __syncthreads();

    // phase 4: stream sorted block region to global (full-line u64 stores)
    for (int k = tid; k < nE; k += 512)
        seg[e0 + k] = stage[k];
}

// ---------------------------------------------------------------- fused SpMM
// Block = dst-bin (192 nodes), fp32 accumulators in LDS (stride-65 pad:
// the 4 ds_add_f32 per edge are 2-way bank conflicts = free). Wave wv walks
// fragments b = wv, wv+8, ...; its 4 16-lane groups process edges of the
// SAME fragment in lockstep (group g takes j = g, g+4, g+8 predicated ->
// covers cnt<=12 in one shot, P(cnt>12) ~ 0.2% at mean 3.93). Lane c of a
// group covers the row as uint2 (8 B x 16 lanes = 128-B row). 8-12 gathers
// in flight per wave x 24 waves/CU (3 blk/CU at 49.9 KB LDS). Bijective
// XCD swizzle maps consecutive bins to one XCD so adjacent-bin seg reads
// share L2 lines. No slots, no deg, no binB.
template <bool LAST>
__global__ __launch_bounds__(512) void spmm_lds(
        const unsigned*           __restrict__ blk_info,
        const unsigned long long* __restrict__ seg,
        const uint2* __restrict__ cur,   // rows of 16 uint2
        uint2*       __restrict__ next,
        const uint2* __restrict__ x0b,
        const uint2* __restrict__ x1b,
        float4*      __restrict__ out) {
    __shared__ float acc[BIN_NODES * ACC_STR];   // 49,920 B
    const int tid = threadIdx.x;
    // bijective XCD swizzle (m204 form): consecutive bins -> same XCD
    const int orig = blockIdx.x;
    const int xcd = orig & 7;
    const int qq = NBINS >> 3, rr = NBINS & 7;
    const int bin = (xcd < rr ? xcd * (qq + 1) : rr * (qq + 1) + (xcd - rr) * qq)
                  + (orig >> 3);
    const int c  = tid & 15;
    const int g4 = (tid >> 4) & 3;
    const int wv = tid >> 6;

    for (int i = tid; i < BIN_NODES * ACC_STR; i += 512) acc[i] = 0.f;
    __syncthreads();

#define PROCESS(E) { \
        unsigned lo_ = (unsigned)(E); \
        int l_ = (int)((unsigned)((E) >> 32)); \
        uint2 hv = cur[((long long)(lo_ & SRC_MASK) << 4) + c]; \
        float q_ = (float)(lo_ >> 19); \
        __half2 h01 = *reinterpret_cast<const __half2*>(&hv.x); \
        __half2 h23 = *reinterpret_cast<const __half2*>(&hv.y); \
        float* ap_ = &acc[l_ * ACC_STR + c * 4]; \
        atomicAdd(ap_ + 0, q_ * __low2float(h01)); \
        atomicAdd(ap_ + 1, q_ * __high2float(h01)); \
        atomicAdd(ap_ + 2, q_ * __low2float(h23)); \
        atomicAdd(ap_ + 3, q_ * __high2float(h23)); }

    const unsigned* ib = blk_info + (long long)bin * NBLK_A;
    for (int b = wv; b < NBLK_A; b += 8) {
        unsigned inf = ib[b];                       // broadcast load
        int cnt = (int)(inf & 0xFFFFu);
        long long base = (long long)b * EPB + (inf >> 16);
        // e==0 when predicated off: l=0,q=0,src=0 -> adds exactly 0 to
        // node 0 via an L1-hot row-0 gather (harmless; avoids 0xNaN).
        unsigned long long e0 = (g4     < cnt) ? seg[base + g4    ] : 0ull;
        unsigned long long e1 = (g4 + 4 < cnt) ? seg[base + g4 + 4] : 0ull;
        PROCESS(e0)
        PROCESS(e1)
        for (int j = g4 + 8; j < cnt; j += 4) {     // rare (P ~ 2%)
            unsigned long long e = seg[base + j];
            PROCESS(e)
        }
    }
#undef PROCESS
    __syncthreads();

    // epilogue: LDS -> global, coalesced
    const long long node0 = (long long)bin * BIN_NODES;
    for (int p = tid; p < BIN_NODES * 16; p += 512) {
        int l = p >> 4, cc = p & 15;
        long long node = node0 + l;
        if (node >= N_NODES) continue;
        const float* ap = &acc[l * ACC_STR + cc * 4];
        float a0 = ap[0] * W_SCALE, a1 = ap[1] * W_SCALE;
        float a2 = ap[2] * W_SCALE, a3 = ap[3] * W_SCALE;
        long long oi = node * 16 + cc;
        if (!LAST) {
            __half2 p01 = __float22half2_rn(make_float2(a0, a1));
            __half2 p23 = __float22half2_rn(make_float2(a2, a3));
            next[oi] = make_uint2(*reinterpret_cast<unsigned*>(&p01),
                                  *reinterpret_cast<unsigned*>(&p23));
        } else {
            uint2 v0 = x0b[oi], v1 = x1b[oi], v2 = cur[oi];
            __half2 u01 = *reinterpret_cast<const __half2*>(&v0.x);
            __half2 u23 = *reinterpret_cast<const __half2*>(&v0.y);
            __half2 w01 = *reinterpret_cast<const __half2*>(&v1.x);
            __half2 w23 = *reinterpret_cast<const __half2*>(&v1.y);
            __half2 z01 = *reinterpret_cast<const __half2*>(&v2.x);
            __half2 z23 = *reinterpret_cast<const __half2*>(&v2.y);
            float4 o;
            o.x = (a0 + __low2float(u01)  + __low2float(w01)  + __low2float(z01))  * 0.25f;
            o.y = (a1 + __high2float(u01) + __high2float(w01) + __high2float(z01)) * 0.25f;
            o.z = (a2 + __low2float(u23)  + __low2float(w23)  + __low2float(z23))  * 0.25f;
            o.w = (a3 + __high2float(u23) + __high2float(w23) + __high2float(z23)) * 0.25f;
            out[oi] = o;
        }
    }
}

// ---------------------------------------------------------------- launch
extern "C" void kernel_launch(void* const* d_in, const int* in_sizes, int n_in,
                              void* d_out, int out_size, void* d_ws, size_t ws_size,
                              hipStream_t stream) {
    const float* user_emb = (const float*)d_in[0];
    const float* item_emb = (const float*)d_in[1];
    const float* ew       = (const float*)d_in[2];
    const int*   es       = (const int*)d_in[3];
    const int*   ed       = (const int*)d_in[4];
    float* out = (float*)d_out;

    // ws layout (slots/deg/binB deleted; NO overlays — seg+blk_info live
    // through all 3 spmm layers):
    //   seg      u64 x NBLK_A*EPB        [0          ..  76,824,576)
    //   blk_info u32 x NBINS*NBLK_A      [76,824,576 ..  86,596,480) (padded)
    //   buf0     fp16 x NELEM  (x0)      [86,596,480 .. 124,996,480)
    //   buf1     fp16 x NELEM  (x1)      [125.0M     .. 163,396,480)
    //   buf2     fp16 x NELEM  (x2)      [163.4M     .. 201,796,480)
    // total ~201.8 MB (verified 235 MB fits).
    unsigned long long* seg = (unsigned long long*)d_ws;
    unsigned* blk_info = (unsigned*)(seg + (long long)NBLK_A * EPB);
    const long long INFOW = (((long long)NBINS * NBLK_A + 15) / 16) * 16;
    __half* buf0 = (__half*)(blk_info + INFOW);
    __half* buf1 = buf0 + NELEM;
    __half* buf2 = buf1 + NELEM;

    const long long init_blocks = (NELEM4 + 255) / 256;

    // ---- build: dst-bin sort only (binB eliminated) ----
    binA_kernel<<<dim3((unsigned)NBLK_A), dim3(512), 0, stream>>>(
        es, ed, ew, seg, blk_info);

    // cur = fp16(all_emb)
    init_kernel<<<dim3((unsigned)init_blocks), dim3(256), 0, stream>>>(
        (const float4*)user_emb, (const float4*)item_emb, (ushort4*)buf0);

    dim3 ng(NBINS), nb(512);
    // ---- 3 fused gather+scatter layers; final mean fused into layer 3 ----
    spmm_lds<false><<<ng, nb, 0, stream>>>(blk_info, seg, (const uint2*)buf0,
        (uint2*)buf1, nullptr, nullptr, nullptr);
    spmm_lds<false><<<ng, nb, 0, stream>>>(blk_info, seg, (const uint2*)buf1,
        (uint2*)buf2, nullptr, nullptr, nullptr);
    spmm_lds<true><<<ng, nb, 0, stream>>>(blk_info, seg, (const uint2*)buf2,
        nullptr, (const uint2*)buf0, (const uint2*)buf1, (float4*)out);
}

// Round 10
// 868.683 us; speedup vs baseline: 24.7509x; 24.7509x over previous
//
#include <hip/hip_runtime.h>
#include <hip/hip_fp16.h>

#define USER_NUM 200000
#define ITEM_NUM 100000
#define N_NODES  300000   // USER_NUM + ITEM_NUM
#define N_EDGES  9600000
#define D        64
#define NELEM    ((long long)N_NODES * D)       // 19,200,000
#define NELEM4   (NELEM / 4)                    // 4,800,000

// Fixed-capacity bucket per node. deg ~ Poisson(32), max for this dataset
// ~60; CAP=96 leaves huge margin (clamp guard below makes OOB impossible).
#define CAP 96

// Slot entry packing: [31:19] = 13-bit weight q (w = q/8191), [18:0] = src id.
#define SRC_MASK 0x7FFFFu
#define W_SCALE  (1.0f / 8191.0f)

// ---- binned bucket-build geometry (round-3 proven: best measured total) ----
// Round-1 lesson: scatter through global cache lines thrashes when open
// partial lines exceed per-XCD L2 — stage scatters in LDS and stream out
// full lines. Round-7/9 lessons: fragment- or slice-granular gather work
// distribution serializes (runs ~1-4 edges kill MLP); the flat per-node
// bucket walk is the latency-tolerant structure. This file = round-3 config
// verbatim (866.5 us measured) + deferred W_SCALE in the gather (r4's
// instruction saving without r4's layout change).
#define BIN_NODES 1024
#define BIN_SHIFT 10
#define NBINS     ((N_NODES + BIN_NODES - 1) / BIN_NODES)   // 293
#define EPB       7168    // edges per block: stage 56 KB + 2x1.2 KB < 64 KB LDS
#define NBLK_A    ((N_EDGES + EPB - 1) / EPB)               // 1340
#define BPG       ((NBLK_A + 15) / 16)                      // 84 blks per group

// ---------------------------------------------------------------- init
// cur = fp16(all_emb). Final layer reconstructs the layer-sum from the
// per-layer fp16 buffers, so out is never RMW'd across layers.
__global__ void init_kernel(const float4* __restrict__ user_emb,
                            const float4* __restrict__ item_emb,
                            ushort4* __restrict__ cur) {
    long long i = (long long)blockIdx.x * blockDim.x + threadIdx.x;
    if (i >= NELEM4) return;
    const long long user4 = (long long)USER_NUM * D / 4;
    float4 v = (i < user4) ? user_emb[i] : item_emb[i - user4];
    __half h0 = __float2half_rn(v.x), h1 = __float2half_rn(v.y);
    __half h2 = __float2half_rn(v.z), h3 = __float2half_rn(v.w);
    cur[i] = make_ushort4(*(unsigned short*)&h0, *(unsigned short*)&h1,
                          *(unsigned short*)&h2, *(unsigned short*)&h3);
}

// ---------------------------------------------------------------- pass A
// Block-local counting sort of EPB edges by bin, staged in LDS.
// Entry: u64 = (local_node << 32) | (q << 19) | src.
// Output: seg[blk*EPB ..] sorted-by-bin (full-line streaming stores), plus
// blk_info[bin][blk] = (start_in_block << 16) | count (both < 7168, fit u16).
__global__ __launch_bounds__(512) void binA_kernel(
        const int*   __restrict__ src,
        const int*   __restrict__ dst,
        const float* __restrict__ w,
        unsigned long long* __restrict__ seg,
        unsigned*           __restrict__ blk_info) {
    __shared__ unsigned long long stage[EPB];   // 57,344 B
    __shared__ int hist[NBINS];                 //  1,172 B
    __shared__ int off[NBINS];                  //  1,172 B
    const int tid = threadIdx.x;
    const long long e0 = (long long)blockIdx.x * EPB;
    long long rem = (long long)N_EDGES - e0;
    const int nE = (int)(rem < EPB ? rem : EPB);   // always a multiple of 4

    for (int i = tid; i < NBINS; i += 512) hist[i] = 0;
    __syncthreads();

    // phase 1: histogram over bins (LDS atomics), int4 loads
    for (int k = tid * 4; k < nE; k += 512 * 4) {
        int4 d4 = *(const int4*)(dst + e0 + k);
        atomicAdd(&hist[d4.x >> BIN_SHIFT], 1);
        atomicAdd(&hist[d4.y >> BIN_SHIFT], 1);
        atomicAdd(&hist[d4.z >> BIN_SHIFT], 1);
        atomicAdd(&hist[d4.w >> BIN_SHIFT], 1);
    }
    __syncthreads();

    // phase 2: Hillis-Steele inclusive scan -> exclusive offsets; emit info
    if (tid < NBINS) off[tid] = hist[tid];
    __syncthreads();
    for (int s = 1; s < NBINS; s <<= 1) {
        int v = 0;
        if (tid < NBINS && tid >= s) v = off[tid - s];
        __syncthreads();
        if (tid < NBINS && tid >= s) off[tid] += v;
        __syncthreads();
    }
    if (tid < NBINS) {
        int excl = off[tid] - hist[tid];
        off[tid] = excl;
        blk_info[(long long)tid * NBLK_A + blockIdx.x] =
            ((unsigned)excl << 16) | (unsigned)hist[tid];
    }
    __syncthreads();

    // phase 3: scatter into LDS stage (8-B LDS writes: no line thrash)
    for (int k = tid * 4; k < nE; k += 512 * 4) {
        int4   s4 = *(const int4*)(src + e0 + k);
        int4   d4 = *(const int4*)(dst + e0 + k);
        float4 w4 = *(const float4*)(w + e0 + k);
#define DO_EDGE(S, DD, W) { \
        unsigned q = (unsigned)((W) * 8191.0f + 0.5f); \
        int bin = (DD) >> BIN_SHIFT; \
        int pos = atomicAdd(&off[bin], 1); \
        stage[pos] = ((unsigned long long)(unsigned)((DD) & (BIN_NODES - 1)) << 32) \
                   | ((q << 19) | (unsigned)(S)); }
        DO_EDGE(s4.x, d4.x, w4.x)
        DO_EDGE(s4.y, d4.y, w4.y)
        DO_EDGE(s4.z, d4.z, w4.z)
        DO_EDGE(s4.w, d4.w, w4.w)
#undef DO_EDGE
    }
    __syncthreads();

    // phase 4: stream sorted block region to global (full-line u64 stores)
    for (int k = tid; k < nE; k += 512)
        seg[e0 + k] = stage[k];
}

// ---------------------------------------------------------------- pass B
// One block per bin. Walks the bin's 1340 fragments (mean 24.5 edges each:
// 32-lane groups, 16 per block). Slot allocation via LDS counters; scattered
// slot stores confined to the bin's 1024*CAP*4 = 384 KB region.
__global__ __launch_bounds__(512) void binB_kernel(
        const unsigned*           __restrict__ blk_info,
        const unsigned long long* __restrict__ seg,
        int*      __restrict__ deg,
        unsigned* __restrict__ slots) {
    __shared__ int dl[BIN_NODES];        // 4 KB
    __shared__ unsigned info[NBLK_A];    // 5.4 KB
    const int bin = blockIdx.x;
    const int tid = threadIdx.x;
    dl[tid] = 0; dl[tid + 512] = 0;
    for (int i = tid; i < NBLK_A; i += 512)
        info[i] = blk_info[(long long)bin * NBLK_A + i];
    __syncthreads();

    const int node0 = bin << BIN_SHIFT;
    const int grp = tid >> 5;            // 16 groups of 32 lanes
    const int gl  = tid & 31;
    int b1 = grp * BPG + BPG;
    if (b1 > NBLK_A) b1 = NBLK_A;
    for (int blk = grp * BPG; blk < b1; ++blk) {
        unsigned inf = info[blk];
        int cnt = (int)(inf & 0xFFFFu);
        long long base = (long long)blk * EPB + (inf >> 16);
        for (int j = gl; j < cnt; j += 32) {
            unsigned long long v = seg[base + j];
            int l = (int)(v >> 32);
            int p = atomicAdd(&dl[l], 1);
            if (p < CAP) slots[(long long)(node0 + l) * CAP + p] = (unsigned)v;
        }
    }
    __syncthreads();

    int node = node0 + tid;
    if (node < N_NODES) deg[node] = dl[tid];
    node += 512;
    if (tid + 512 < BIN_NODES && node < N_NODES) deg[node] = dl[tid + 512];
}

// ---------------------------------------------------------------- gather SpMM
// Round-3 proven kernel (191.1 us/layer, best measured). TWO nodes per wave:
// half = lane>>5 picks the node, col = lane&31 covers the 64-dim row as
// half2 (4 B/lane x 32 lanes = 128-B row). 8-deep unroll = 16 rows in
// flight/wave. Weight scale DEFERRED to the epilogue (acc = sum q*x,
// |acc| <= ~3e7, fp32-exact-safe) — saves one v_mul per edge vs r3.
// !LAST: write fp16 layer output only. LAST: fuse mean from fp16 buffers.
template <bool LAST>
__global__ void spmm_gather(const int*      __restrict__ deg,
                            const unsigned* __restrict__ slots,
                            const __half2*  __restrict__ cur,   // rows of 32 half2
                            __half2*        __restrict__ next,
                            const __half2*  __restrict__ x0b,
                            const __half2*  __restrict__ x1b,
                            float2*         __restrict__ out) {
    long long t = (long long)blockIdx.x * blockDim.x + threadIdx.x;
    int wave = (int)(t >> 6);
    int lane = (int)(t & 63);
    int half = lane >> 5;
    int col  = lane & 31;
    int node = wave * 2 + half;
    if (node >= N_NODES) return;
    int n = deg[node];
    if (n > CAP) n = CAP;
    const unsigned* sl = slots + (long long)node * CAP;
    float accx = 0.f, accy = 0.f;
    float bccx = 0.f, bccy = 0.f;
    int i = 0;
    for (; i + 7 < n; i += 8) {        // 8-unroll x 2 halves = 16 rows in flight
        uint4 ea = *(const uint4*)(sl + i);
        uint4 eb = *(const uint4*)(sl + i + 4);
        __half2 x0 = cur[(long long)(ea.x & SRC_MASK) * 32 + col];
        __half2 x1 = cur[(long long)(ea.y & SRC_MASK) * 32 + col];
        __half2 x2 = cur[(long long)(ea.z & SRC_MASK) * 32 + col];
        __half2 x3 = cur[(long long)(ea.w & SRC_MASK) * 32 + col];
        __half2 x4 = cur[(long long)(eb.x & SRC_MASK) * 32 + col];
        __half2 x5 = cur[(long long)(eb.y & SRC_MASK) * 32 + col];
        __half2 x6 = cur[(long long)(eb.z & SRC_MASK) * 32 + col];
        __half2 x7 = cur[(long long)(eb.w & SRC_MASK) * 32 + col];
        float q0 = (float)(ea.x >> 19);
        float q1 = (float)(ea.y >> 19);
        float q2 = (float)(ea.z >> 19);
        float q3 = (float)(ea.w >> 19);
        float q4 = (float)(eb.x >> 19);
        float q5 = (float)(eb.y >> 19);
        float q6 = (float)(eb.z >> 19);
        float q7 = (float)(eb.w >> 19);
        float2 f0 = __half22float2(x0);
        float2 f1 = __half22float2(x1);
        float2 f2 = __half22float2(x2);
        float2 f3 = __half22float2(x3);
        float2 f4 = __half22float2(x4);
        float2 f5 = __half22float2(x5);
        float2 f6 = __half22float2(x6);
        float2 f7 = __half22float2(x7);
        accx = fmaf(q0, f0.x, accx); accy = fmaf(q0, f0.y, accy);
        bccx = fmaf(q1, f1.x, bccx); bccy = fmaf(q1, f1.y, bccy);
        accx = fmaf(q2, f2.x, accx); accy = fmaf(q2, f2.y, accy);
        bccx = fmaf(q3, f3.x, bccx); bccy = fmaf(q3, f3.y, bccy);
        accx = fmaf(q4, f4.x, accx); accy = fmaf(q4, f4.y, accy);
        bccx = fmaf(q5, f5.x, bccx); bccy = fmaf(q5, f5.y, bccy);
        accx = fmaf(q6, f6.x, accx); accy = fmaf(q6, f6.y, accy);
        bccx = fmaf(q7, f7.x, bccx); bccy = fmaf(q7, f7.y, bccy);
    }
    for (; i + 3 < n; i += 4) {
        uint4 ea = *(const uint4*)(sl + i);
        __half2 x0 = cur[(long long)(ea.x & SRC_MASK) * 32 + col];
        __half2 x1 = cur[(long long)(ea.y & SRC_MASK) * 32 + col];
        __half2 x2 = cur[(long long)(ea.z & SRC_MASK) * 32 + col];
        __half2 x3 = cur[(long long)(ea.w & SRC_MASK) * 32 + col];
        float q0 = (float)(ea.x >> 19);
        float q1 = (float)(ea.y >> 19);
        float q2 = (float)(ea.z >> 19);
        float q3 = (float)(ea.w >> 19);
        float2 f0 = __half22float2(x0);
        float2 f1 = __half22float2(x1);
        float2 f2 = __half22float2(x2);
        float2 f3 = __half22float2(x3);
        accx = fmaf(q0, f0.x, accx); accy = fmaf(q0, f0.y, accy);
        bccx = fmaf(q1, f1.x, bccx); bccy = fmaf(q1, f1.y, bccy);
        accx = fmaf(q2, f2.x, accx); accy = fmaf(q2, f2.y, accy);
        bccx = fmaf(q3, f3.x, bccx); bccy = fmaf(q3, f3.y, bccy);
    }
    for (; i < n; ++i) {
        unsigned e0 = sl[i];
        __half2 x0 = cur[(long long)(e0 & SRC_MASK) * 32 + col];
        float q0 = (float)(e0 >> 19);
        float2 f0 = __half22float2(x0);
        accx = fmaf(q0, f0.x, accx); accy = fmaf(q0, f0.y, accy);
    }
    accx = (accx + bccx) * W_SCALE;
    accy = (accy + bccy) * W_SCALE;
    long long oi = (long long)node * 32 + col;
    if (!LAST) {
        __half2 h; h.x = __float2half_rn(accx); h.y = __float2half_rn(accy);
        next[oi] = h;
    } else {
        float2 f0 = __half22float2(x0b[oi]);
        float2 f1 = __half22float2(x1b[oi]);
        float2 f2 = __half22float2(cur[oi]);
        float2 o;
        o.x = (f0.x + f1.x + f2.x + accx) * 0.25f;
        o.y = (f0.y + f1.y + f2.y + accy) * 0.25f;
        out[oi] = o;
    }
}

// ---------------------------------------------------------------- launch
extern "C" void kernel_launch(void* const* d_in, const int* in_sizes, int n_in,
                              void* d_out, int out_size, void* d_ws, size_t ws_size,
                              hipStream_t stream) {
    const float* user_emb = (const float*)d_in[0];
    const float* item_emb = (const float*)d_in[1];
    const float* ew       = (const float*)d_in[2];
    const int*   es       = (const int*)d_in[3];
    const int*   ed       = (const int*)d_in[4];
    float* out = (float*)d_out;

    // ws layout:
    //   slots    u32 x N_NODES*CAP       [0          .. 115,200,000)
    //   deg      int x N_NODES           [115.2M     .. 116,400,000)
    //   buf0     fp16 x NELEM  (x0)      [116.4M     .. 154,800,000)
    //   buf1     fp16 x NELEM  (x1)      [154.8M     .. 193,200,000)
    //   buf2     fp16 x NELEM  (x2)      [193.2M     .. 231,600,000)
    //   blk_info u32 x NBINS*NBLK_A      [231.6M     .. 233,170,480)
    //   seg      u64 x NBLK_A*EPB overlays buf0..buf2-head (dead before init)
    // max ~233.2 MB (verified 235 MB fits). seg/blk_info are produced by
    // binA, consumed by binB; buf0 is written by init AFTER binB and buf2
    // first written by layer 2 — stream order makes overlays safe.
    unsigned* slots = (unsigned*)d_ws;
    int*      deg   = (int*)(slots + (long long)N_NODES * CAP);
    __half*   buf0  = (__half*)(deg + N_NODES);
    __half*   buf1  = buf0 + NELEM;
    __half*   buf2  = buf1 + NELEM;
    unsigned* blk_info = (unsigned*)(buf2 + NELEM);
    unsigned long long* seg = (unsigned long long*)buf0;

    const int B = 256;
    const long long node_waves  = (N_NODES + 1) / 2;                       // 150000
    const long long node_blocks = (node_waves * 64 + B - 1) / B;           // 37500
    const long long init_blocks = (NELEM4 + B - 1) / B;

    // ---- LDS-staged binned bucket build (no global atomics, no memset) ----
    binA_kernel<<<dim3((unsigned)NBLK_A), dim3(512), 0, stream>>>(
        es, ed, ew, seg, blk_info);
    binB_kernel<<<dim3((unsigned)NBINS), dim3(512), 0, stream>>>(
        blk_info, seg, deg, slots);

    // cur = fp16(all_emb). After binB (seg overlay).
    init_kernel<<<dim3((unsigned)init_blocks), dim3(B), 0, stream>>>(
        (const float4*)user_emb, (const float4*)item_emb, (ushort4*)buf0);

    dim3 ng((unsigned)node_blocks), nb(B);
    // ---- 3 gather layers; final mean fused into layer 3 ----
    spmm_gather<false><<<ng, nb, 0, stream>>>(deg, slots, (const __half2*)buf0,
        (__half2*)buf1, nullptr, nullptr, nullptr);
    spmm_gather<false><<<ng, nb, 0, stream>>>(deg, slots, (const __half2*)buf1,
        (__half2*)buf2, nullptr, nullptr, nullptr);
    spmm_gather<true><<<ng, nb, 0, stream>>>(deg, slots, (const __half2*)buf2,
        nullptr, (const __half2*)buf0, (const __half2*)buf1, (float2*)out);
}